// Round 2
// baseline (3585.353 us; speedup 1.0000x reference)
//
#include <hip/hip_runtime.h>

// ContinuousLSTMLayer B=256,S=512,F=64,H=128; 8192 sequential RK4 stages.
// v6 = v5 + hard schedule fences. v5 PMC: MfmaUtil 52% of 1114cy/stage =
// 580cy pipe (= the 620cy model); ~500cy idle. Diagnosis: within v5's one big
// scheduling region the compiler sank the trans-heavy deferred VALU below the
// MFMA cluster; with in-order issue the pipes ALTERNATE (620 MFMA + ~270 VALU
// + head/tail = 1114) instead of overlapping. Fix:
//   sched_barrier(0) fences pin per-stage order:
//     [ds_read A] < [deferred i/f/g VALU + c-path + tc  (~136cy/2 waves,
//      fills the ~120cy ds_read latency)] < [o-chain MFMA] < [i/f/g MFMA
//      issue + po/ao] < [minimal tail: kh, h-update, cvt, ds_write]
//   barrier = lgkmcnt(0)-only (raw s_barrier) -- no vmcnt/expcnt drain for
//   the x-prefetch global load / out store (reg deps handle those).
// Carries (i/f/g accumulators) still cross the barrier in registers; carry
// extraction (pi/pf/pg) happens at the top of the deferred region so the new
// MFMAs may overwrite them. RK role logic unchanged from v5 (proven).

#define B_N 256
#define S_N 512
#define F_N 64
#define H_N 128

typedef _Float16 v8h __attribute__((ext_vector_type(8)));
typedef float v4f __attribute__((ext_vector_type(4)));

#define PIN_V(x) asm("" : "+v"(x))
#define MFMA16(a, b, c) __builtin_amdgcn_mfma_f32_16x16x32_f16((a), (b), (c), 0, 0, 0)
#define SB0() __builtin_amdgcn_sched_barrier(0)
// lgkmcnt-only barrier: LDS writes visible, no vmcnt drain. SB0 before the
// asm keeps ds_write above it; SB0 after s_barrier blocks MFMA/ds hoisting
// (rule: compiler may hoist reg-only MFMA past inline-asm waitcnt).
#define BAR() do { SB0(); \
                   asm volatile("s_waitcnt lgkmcnt(0)" ::: "memory"); \
                   __builtin_amdgcn_s_barrier(); SB0(); } while (0)

// sigmoid via exp2 + rcp (overflow-safe: rcp(inf)=0)
static __device__ __forceinline__ float sigm(float x) {
  float e = __builtin_amdgcn_exp2f(-1.442695040888963f * x);
  return __builtin_amdgcn_rcpf(1.0f + e);
}

__global__ void __launch_bounds__(512, 2) clstm_mfma6(
    const float* __restrict__ x,    // [B,S,F] f32
    const float* __restrict__ td,   // [B,S]   f32
    const float* __restrict__ Wi, const float* __restrict__ bi,
    const float* __restrict__ Wf, const float* __restrict__ bff,
    const float* __restrict__ Wo, const float* __restrict__ bo,
    const float* __restrict__ Wg, const float* __restrict__ bg,
    float* __restrict__ out)        // [B,S,H] f32
{
  const int b    = blockIdx.x;
  const int t    = threadIdx.x;
  const int wv   = t >> 6;
  const int l    = t & 63;
  const int col  = l & 15;
  const int quad = l >> 4;
  const int n    = wv * 16 + col;

  const float* Wptr[4] = {Wi, Wf, Wo, Wg};

  // Resident B-frags pinned to arch VGPRs (v4-proven).
  v8h Bh[4][4];
  v8h Bx[4][2];
#pragma unroll
  for (int g = 0; g < 4; ++g) {
    const float* W = Wptr[g];
#pragma unroll
    for (int kt = 0; kt < 4; ++kt) {
      v8h f;
#pragma unroll
      for (int j = 0; j < 8; ++j)
        f[j] = (_Float16)W[(64 + kt * 32 + quad * 8 + j) * H_N + n];
      Bh[g][kt] = f;
      PIN_V(Bh[g][kt]);
    }
#pragma unroll
    for (int kt = 0; kt < 2; ++kt) {
      v8h f;
#pragma unroll
      for (int j = 0; j < 8; ++j)
        f[j] = (_Float16)W[(kt * 32 + quad * 8 + j) * H_N + n];
      Bx[g][kt] = f;
      PIN_V(Bx[g][kt]);
    }
  }
  float bias[4];
#pragma unroll
  for (int g = 0; g < 4; ++g)
    bias[g] = (g == 0 ? bi : g == 1 ? bff : g == 2 ? bo : bg)[n];

  __shared__ alignas(16) _Float16 lds_h[2][H_N];  // double-buffered h (f16)
  __shared__ alignas(16) _Float16 lds_x[F_N];     // current x_t (f16)
  __shared__ float lds_td[S_N];

  lds_td[t] = td[b * S_N + t];
  if (t < 32) {
    const float* xr = x + (size_t)b * S_N * F_N;
    lds_x[2 * t]     = (_Float16)xr[2 * t];
    lds_x[2 * t + 1] = (_Float16)xr[2 * t + 1];
  }
  if (t < H_N) lds_h[0][t] = (_Float16)0.0f;
  // first BAR() in the loop covers setup visibility (lgkmcnt(0) + barrier)

  float h0v = 0.f, c0v = 0.f;
  float h_ev = 0.f, c_ev = 0.f;
  float sum_h = 0.f, sum_c = 0.f;
  float dt = 0.f, hdt = 0.f, d6 = 0.f, d6p = 0.f;
  const v4f zf = {0.f, 0.f, 0.f, 0.f};
  // carried i/f/g MFMA accumulators (consumed one stage later)
  v4f ci2 = zf, ci3 = zf, cf2 = zf, cf3 = zf, cg2 = zf, cg3 = zf;
  v4f xpD[4] = {zf, zf, zf, zf};
  float xn0 = 0.f, xn1 = 0.f;

  for (int s = 0; s < S_N; ++s) {
#pragma unroll
    for (int ode = 0; ode < 4; ++ode) {
#pragma unroll
      for (int st = 0; st < 4; ++st) {
        BAR();                                 // h(stage) now visible
        // ---- S0: A-frag ds_reads issue ----
        const _Float16* hb = lds_h[st & 1];
        v8h ah0 = *(const v8h*)(hb + quad * 8);
        v8h ah1 = *(const v8h*)(hb + 32 + quad * 8);
        v8h ah2 = *(const v8h*)(hb + 64 + quad * 8);
        v8h ah3 = *(const v8h*)(hb + 96 + quad * 8);

        if (ode == 0 && st == 0) {
          // per-timestep: dt scales, x-projection (8 MFMAs, amortized /16),
          // next-x prefetch issue
          dt  = fminf(lds_td[s], 1.0f) * 0.25f;  // MAX_DT / ODE_STEPS
          hdt = 0.5f * dt;
          d6  = dt * (1.0f / 6.0f);
          v8h ax0 = *(const v8h*)(lds_x + quad * 8);
          v8h ax1 = *(const v8h*)(lds_x + 32 + quad * 8);
#pragma unroll
          for (int g = 0; g < 4; ++g) {
            float bv = bias[g];
            v4f cbv = {bv, bv, bv, bv};
            v4f a = MFMA16(ax0, Bx[g][0], cbv);
            xpD[g] = MFMA16(ax1, Bx[g][1], a);
          }
          xn0 = 0.f; xn1 = 0.f;
          if (t < 32 && s + 1 < S_N) {
            const float* xr = x + (size_t)(b * S_N + s + 1) * F_N;
            xn0 = xr[2 * t]; xn1 = xr[2 * t + 1];
          }
        }
        SB0();

        // ---- S1: deferred i/f/g nonlinearity + c-path of PREVIOUS stage ----
        // fenced BEFORE the o-chain: its ~26 VALU ops (8 trans) per wave fill
        // the ds_read latency window on the VALU pipe.
        float tc;
        {
          const int pr = (st == 0) ? 3 : st - 1;   // prev stage's RK role
          float pi = ci2[0] + ci3[0];              // carry extract (frees regs
          float pf = cf2[0] + cf3[0];              //  for this stage's MFMAs)
          float pg = cg2[0] + cg3[0];
          float ai = sigm(pi);
          float af = sigm(pf);
          float ag = fmaf(2.0f, sigm(2.0f * pg), -1.0f);   // tanh
          float kc = fmaf(ai, ag, (af - 1.0f) * c_ev);     // i*g + f*c - c
          float cnx;
          if (pr == 0)      { sum_c = kc;                      cnx = fmaf(hdt, kc, c0v); }
          else if (pr == 1) { sum_c = fmaf(2.f, kc, sum_c);    cnx = fmaf(hdt, kc, c0v); }
          else if (pr == 2) { sum_c = fmaf(2.f, kc, sum_c);    cnx = fmaf(dt, kc, c0v); }
          else {
            float sc = sum_c + kc;
            float dd = (ode == 0 && st == 0) ? d6p : d6;     // timestep crossing
            c0v = fmaf(dd, sc, c0v);
            cnx = c0v;
          }
          c_ev = cnx;
          tc = fmaf(2.0f, sigm(2.0f * c_ev), -1.0f);         // tanh(c_ev)
        }
        SB0();

        // ---- S2: o-chain (the only MFMAs on the h critical path) ----
        v4f co2 = MFMA16(ah0, Bh[2][0], xpD[2]);
        co2     = MFMA16(ah1, Bh[2][1], co2);
        v4f co3 = MFMA16(ah2, Bh[2][2], zf);
        co3     = MFMA16(ah3, Bh[2][3], co3);
        SB0();

        // ---- S3: i/f/g issue (consumed next stage) + o preact ----
        ci2 = MFMA16(ah0, Bh[0][0], xpD[0]);
        ci2 = MFMA16(ah1, Bh[0][1], ci2);
        ci3 = MFMA16(ah2, Bh[0][2], zf);
        ci3 = MFMA16(ah3, Bh[0][3], ci3);
        cf2 = MFMA16(ah0, Bh[1][0], xpD[1]);
        cf2 = MFMA16(ah1, Bh[1][1], cf2);
        cf3 = MFMA16(ah2, Bh[1][2], zf);
        cf3 = MFMA16(ah3, Bh[1][3], cf3);
        cg2 = MFMA16(ah0, Bh[3][0], xpD[3]);
        cg2 = MFMA16(ah1, Bh[3][1], cg2);
        cg3 = MFMA16(ah2, Bh[3][2], zf);
        cg3 = MFMA16(ah3, Bh[3][3], cg3);
        float po = co2[0] + co3[0];
        float ao = sigm(po);
        SB0();

        // ---- S4: minimal o tail -> h update -> LDS write ----
        float kh = fmaf(ao, tc, -h_ev);                      // o*tanh(c) - h
        float hnx;
        if (st == 0)      { sum_h = kh;                      hnx = fmaf(hdt, kh, h0v); }
        else if (st == 1) { sum_h = fmaf(2.f, kh, sum_h);    hnx = fmaf(hdt, kh, h0v); }
        else if (st == 2) { sum_h = fmaf(2.f, kh, sum_h);    hnx = fmaf(dt, kh, h0v); }
        else {
          float sh = sum_h + kh;
          h0v = fmaf(d6, sh, h0v);
          hnx = h0v;
        }
        h_ev = hnx;
        if (quad == 0) lds_h[(st & 1) ^ 1][n] = (_Float16)hnx;

        if (ode == 3 && st == 3) {
          if (t < 32 && s + 1 < S_N) {
            lds_x[2 * t]     = (_Float16)xn0;   // vmcnt reg-dep wait here
            lds_x[2 * t + 1] = (_Float16)xn1;
          }
          if (quad == 0) out[(size_t)(b * S_N + s) * H_N + n] = h0v;
          d6p = d6;
        }
      }
    }
  }
}

extern "C" void kernel_launch(void* const* d_in, const int* in_sizes, int n_in,
                              void* d_out, int out_size, void* d_ws, size_t ws_size,
                              hipStream_t stream) {
  (void)in_sizes; (void)n_in; (void)d_ws; (void)ws_size; (void)out_size;
  clstm_mfma6<<<B_N, 512, 0, stream>>>(
      (const float*)d_in[0],  // x
      (const float*)d_in[1],  // time_diffs
      (const float*)d_in[2], (const float*)d_in[3],   // W_i, b_i
      (const float*)d_in[4], (const float*)d_in[5],   // W_f, b_f
      (const float*)d_in[6], (const float*)d_in[7],   // W_o, b_o
      (const float*)d_in[8], (const float*)d_in[9],   // W_g, b_g
      (float*)d_out);
}

// Round 3
// 3284.066 us; speedup vs baseline: 1.0917x; 1.0917x over previous
//
#include <hip/hip_runtime.h>

// ContinuousLSTMLayer B=256,S=512,F=64,H=128; 8192 sequential RK4 stages.
// v7 = v5 + ifg-MFMAs issued ACROSS the barrier.
// Model from v5/v6 PMC: stage 1114cy = 620cy MFMA pipe (hard floor: 128
// MFMAs/CU-stage @4.85cy) + ~490cy bubble. Bubble cause: in-order issue —
// a wave can't issue its tail until its 12 ifg MFMAs are ACCEPTED by the
// matrix pipe (1/19.4cy/SIMD, 2 waves alternating => last accepted ~590cy),
// so tail+barrier+ds_read(120cy) all land AFTER the pipe drains.
// Fix: ifg MFMAs use only prev-stage A-frags (regs) + xp -- no LDS dep --
// so issue them AFTER the barrier, inside the next stage's ds_read window:
//   BAR -> ds_read ah(s) -> ifg(s-1) [12 MFMA] -> o(s) [4 indep MFMA]
//       -> S1 (c-path of s-1; stalls on fresh carries, overlapping o's pipe
//          wait) -> tail po->ao->kh->hnx->ds_write -> BAR
// Barrier is lgkm-only (no vmcnt drain: x-prefetch/out-store are reg-dep
// waited; kills the every-16th-stage HBM-latency stall at __syncthreads).
// Math identical to v5 (c-path deferred one stage; period-0 bootstrap =
// zero carries neutralized by d6p=0). o-chain split 2x2 -> 4x1 (one less
// MFMA-latency on the po path). ah saved to ap each stage for next ifg.

#define B_N 256
#define S_N 512
#define F_N 64
#define H_N 128

typedef _Float16 v8h __attribute__((ext_vector_type(8)));
typedef float v4f __attribute__((ext_vector_type(4)));

#define PIN_V(x) asm("" : "+v"(x))
#define MFMA16(a, b, c) __builtin_amdgcn_mfma_f32_16x16x32_f16((a), (b), (c), 0, 0, 0)
#define SB0() __builtin_amdgcn_sched_barrier(0)
// lgkm-only barrier. Reg-only MFMAs may hoist across it (rule #18) -- here
// that is SAFE and GOOD: ifg operands are prev-stage regs; memory ops are
// ordered by the "memory" clobber.
#define BAR() do { SB0(); \
                   asm volatile("s_waitcnt lgkmcnt(0)" ::: "memory"); \
                   __builtin_amdgcn_s_barrier(); SB0(); } while (0)

// sigmoid via exp2 + rcp (overflow-safe: rcp(inf)=0)
static __device__ __forceinline__ float sigm(float x) {
  float e = __builtin_amdgcn_exp2f(-1.442695040888963f * x);
  return __builtin_amdgcn_rcpf(1.0f + e);
}

__global__ void __launch_bounds__(512, 2) clstm_mfma7(
    const float* __restrict__ x,    // [B,S,F] f32
    const float* __restrict__ td,   // [B,S]   f32
    const float* __restrict__ Wi, const float* __restrict__ bi,
    const float* __restrict__ Wf, const float* __restrict__ bff,
    const float* __restrict__ Wo, const float* __restrict__ bo,
    const float* __restrict__ Wg, const float* __restrict__ bg,
    float* __restrict__ out)        // [B,S,H] f32
{
  const int b    = blockIdx.x;
  const int t    = threadIdx.x;
  const int wv   = t >> 6;
  const int l    = t & 63;
  const int col  = l & 15;
  const int quad = l >> 4;
  const int n    = wv * 16 + col;

  const float* Wptr[4] = {Wi, Wf, Wo, Wg};

  // Resident B-frags pinned to arch VGPRs (v4-proven).
  v8h Bh[4][4];
  v8h Bx[4][2];
#pragma unroll
  for (int g = 0; g < 4; ++g) {
    const float* W = Wptr[g];
#pragma unroll
    for (int kt = 0; kt < 4; ++kt) {
      v8h f;
#pragma unroll
      for (int j = 0; j < 8; ++j)
        f[j] = (_Float16)W[(64 + kt * 32 + quad * 8 + j) * H_N + n];
      Bh[g][kt] = f;
      PIN_V(Bh[g][kt]);
    }
#pragma unroll
    for (int kt = 0; kt < 2; ++kt) {
      v8h f;
#pragma unroll
      for (int j = 0; j < 8; ++j)
        f[j] = (_Float16)W[(kt * 32 + quad * 8 + j) * H_N + n];
      Bx[g][kt] = f;
      PIN_V(Bx[g][kt]);
    }
  }
  float bias[4];
#pragma unroll
  for (int g = 0; g < 4; ++g)
    bias[g] = (g == 0 ? bi : g == 1 ? bff : g == 2 ? bo : bg)[n];

  __shared__ alignas(16) _Float16 lds_h[2][H_N];  // double-buffered h (f16)
  __shared__ alignas(16) _Float16 lds_x[F_N];     // current x_t (f16)
  __shared__ float lds_td[S_N];

  lds_td[t] = td[b * S_N + t];
  if (t < 32) {
    const float* xr = x + (size_t)b * S_N * F_N;
    lds_x[2 * t]     = (_Float16)xr[2 * t];
    lds_x[2 * t + 1] = (_Float16)xr[2 * t + 1];
  }
  if (t < H_N) lds_h[0][t] = (_Float16)0.0f;
  // first BAR() covers setup visibility (lgkmcnt(0) + s_barrier)

  float h0v = 0.f, c0v = 0.f;
  float h_ev = 0.f, c_ev = 0.f;
  float sum_h = 0.f, sum_c = 0.f;
  float dt = 0.f, hdt = 0.f, d6 = 0.f, d6p = 0.f;
  const v4f zf = {0.f, 0.f, 0.f, 0.f};
  const v8h zh = {(_Float16)0, (_Float16)0, (_Float16)0, (_Float16)0,
                  (_Float16)0, (_Float16)0, (_Float16)0, (_Float16)0};
  // carried i/f/g accumulators (issued at period top, consumed by S1 same
  // period) + prev-stage A-frags + per-gate x-projections
  v4f ci2 = zf, ci3 = zf, cf2 = zf, cf3 = zf, cg2 = zf, cg3 = zf;
  v4f xpI = zf, xpF = zf, xpO = zf, xpG = zf;
  v8h ap0 = zh, ap1 = zh, ap2 = zh, ap3 = zh;
  float xn0 = 0.f, xn1 = 0.f;

  for (int s = 0; s < S_N; ++s) {
#pragma unroll
    for (int ode = 0; ode < 4; ++ode) {
#pragma unroll
      for (int st = 0; st < 4; ++st) {
        BAR();                                 // h(stage) now visible
        // ---- ds_reads: current A-frags ----
        const _Float16* hb = lds_h[st & 1];
        v8h ah0 = *(const v8h*)(hb + quad * 8);
        v8h ah1 = *(const v8h*)(hb + 32 + quad * 8);
        v8h ah2 = *(const v8h*)(hb + 64 + quad * 8);
        v8h ah3 = *(const v8h*)(hb + 96 + quad * 8);

        // ---- ifg(prev stage) issue: reg-only (ap + xpI/F/G), fills the
        //      ds_read latency window and backs up the pipe ----
        if (st != 0 || ode != 0 || s != 0) {   // constant-folds except (0,0)
          ci2 = MFMA16(ap0, Bh[0][0], xpI);
          ci2 = MFMA16(ap1, Bh[0][1], ci2);
          ci3 = MFMA16(ap2, Bh[0][2], zf);
          ci3 = MFMA16(ap3, Bh[0][3], ci3);
          cf2 = MFMA16(ap0, Bh[1][0], xpF);
          cf2 = MFMA16(ap1, Bh[1][1], cf2);
          cf3 = MFMA16(ap2, Bh[1][2], zf);
          cf3 = MFMA16(ap3, Bh[1][3], cf3);
          cg2 = MFMA16(ap0, Bh[3][0], xpG);
          cg2 = MFMA16(ap1, Bh[3][1], cg2);
          cg3 = MFMA16(ap2, Bh[3][2], zf);
          cg3 = MFMA16(ap3, Bh[3][3], cg3);
        }
        SB0();                                 // pin ifg before xp/o

        if (ode == 0 && st == 0) {
          // per-timestep: dt scales, x-projection (8 MFMAs, after ifg so
          // ifg still sees the OLD xpI/F/G), next-x prefetch issue
          dt  = fminf(lds_td[s], 1.0f) * 0.25f;  // MAX_DT / ODE_STEPS
          hdt = 0.5f * dt;
          d6  = dt * (1.0f / 6.0f);
          v8h ax0 = *(const v8h*)(lds_x + quad * 8);
          v8h ax1 = *(const v8h*)(lds_x + 32 + quad * 8);
          {
            v4f cb = {bias[0], bias[0], bias[0], bias[0]};
            v4f a = MFMA16(ax0, Bx[0][0], cb);  xpI = MFMA16(ax1, Bx[0][1], a);
          }
          {
            v4f cb = {bias[1], bias[1], bias[1], bias[1]};
            v4f a = MFMA16(ax0, Bx[1][0], cb);  xpF = MFMA16(ax1, Bx[1][1], a);
          }
          {
            v4f cb = {bias[2], bias[2], bias[2], bias[2]};
            v4f a = MFMA16(ax0, Bx[2][0], cb);  xpO = MFMA16(ax1, Bx[2][1], a);
          }
          {
            v4f cb = {bias[3], bias[3], bias[3], bias[3]};
            v4f a = MFMA16(ax0, Bx[3][0], cb);  xpG = MFMA16(ax1, Bx[3][1], a);
          }
          xn0 = 0.f; xn1 = 0.f;
          if (t < 32 && s + 1 < S_N) {
            const float* xr = x + (size_t)(b * S_N + s + 1) * F_N;
            xn0 = xr[2 * t]; xn1 = xr[2 * t + 1];
          }
        }

        // ---- o(cur) issue: 4 independent 1-deep MFMAs ----
        v4f co0 = MFMA16(ah0, Bh[2][0], xpO);
        v4f co1 = MFMA16(ah1, Bh[2][1], zf);
        v4f co2 = MFMA16(ah2, Bh[2][2], zf);
        v4f co3 = MFMA16(ah3, Bh[2][3], zf);
        SB0();                                 // o issued before S1's stall

        // ---- S1: deferred c-path of PREVIOUS stage (stalls on fresh
        //      carries; overlaps o's pipe wait) ----
        float tc;
        {
          const int pr = (st == 0) ? 3 : st - 1;   // prev stage's RK role
          float pi = ci2[0] + ci3[0];
          float pf = cf2[0] + cf3[0];
          float pg = cg2[0] + cg3[0];
          float ai = sigm(pi);
          float af = sigm(pf);
          float ag = fmaf(2.0f, sigm(2.0f * pg), -1.0f);   // tanh
          float kc = fmaf(ai, ag, (af - 1.0f) * c_ev);     // i*g + f*c - c
          float cnx;
          if (pr == 0)      { sum_c = kc;                      cnx = fmaf(hdt, kc, c0v); }
          else if (pr == 1) { sum_c = fmaf(2.f, kc, sum_c);    cnx = fmaf(hdt, kc, c0v); }
          else if (pr == 2) { sum_c = fmaf(2.f, kc, sum_c);    cnx = fmaf(dt, kc, c0v); }
          else {
            float sc = sum_c + kc;
            float dd = (ode == 0 && st == 0) ? d6p : d6;     // timestep crossing
            c0v = fmaf(dd, sc, c0v);
            cnx = c0v;
          }
          c_ev = cnx;
          tc = fmaf(2.0f, sigm(2.0f * c_ev), -1.0f);         // tanh(c_ev)
        }

        // ---- tail: o preact -> h update -> LDS write ----
        float po = (co0[0] + co1[0]) + (co2[0] + co3[0]);
        float ao = sigm(po);
        float kh = fmaf(ao, tc, -h_ev);                      // o*tanh(c) - h
        float hnx;
        if (st == 0)      { sum_h = kh;                      hnx = fmaf(hdt, kh, h0v); }
        else if (st == 1) { sum_h = fmaf(2.f, kh, sum_h);    hnx = fmaf(hdt, kh, h0v); }
        else if (st == 2) { sum_h = fmaf(2.f, kh, sum_h);    hnx = fmaf(dt, kh, h0v); }
        else {
          float sh = sum_h + kh;
          h0v = fmaf(d6, sh, h0v);
          hnx = h0v;
        }
        h_ev = hnx;
        if (quad == 0) lds_h[(st & 1) ^ 1][n] = (_Float16)hnx;

        if (ode == 3 && st == 3) {
          if (t < 32 && s + 1 < S_N) {
            lds_x[2 * t]     = (_Float16)xn0;   // reg-dep vmcnt wait here
            lds_x[2 * t + 1] = (_Float16)xn1;
          }
          if (quad == 0) out[(size_t)(b * S_N + s) * H_N + n] = h0v;
          d6p = d6;
        }

        // save A-frags for next period's ifg issue
        ap0 = ah0; ap1 = ah1; ap2 = ah2; ap3 = ah3;
      }
    }
  }
}

extern "C" void kernel_launch(void* const* d_in, const int* in_sizes, int n_in,
                              void* d_out, int out_size, void* d_ws, size_t ws_size,
                              hipStream_t stream) {
  (void)in_sizes; (void)n_in; (void)d_ws; (void)ws_size; (void)out_size;
  clstm_mfma7<<<B_N, 512, 0, stream>>>(
      (const float*)d_in[0],  // x
      (const float*)d_in[1],  // time_diffs
      (const float*)d_in[2], (const float*)d_in[3],   // W_i, b_i
      (const float*)d_in[4], (const float*)d_in[5],   // W_f, b_f
      (const float*)d_in[6], (const float*)d_in[7],   // W_o, b_o
      (const float*)d_in[8], (const float*)d_in[9],   // W_g, b_g
      (float*)d_out);
}